// Round 13
// baseline (127.327 us; speedup 1.0000x reference)
//
#include <hip/hip_runtime.h>

// Problem constants
#define NROWS 512          // N
#define FEAT  8192         // NUM_CHANNELS*4*4
#define BDIM  64
#define CDIM  16
#define MCOLS 1024         // BDIM*CDIM
#define OUTC  8256         // FEAT + BDIM
#define KSPLIT 8
#define KCHUNK (FEAT / KSPLIT)     // 1024
#define KSTEPS (KCHUNK / 64)       // 16
#define MSIZE  (NROWS * MCOLS)     // 524288 floats = 2 MB

typedef __bf16 bf16x8 __attribute__((ext_vector_type(8)));
typedef float  floatx4 __attribute__((ext_vector_type(4)));

static __device__ __forceinline__ unsigned short f2bf(float f) {
    unsigned int x = __builtin_bit_cast(unsigned int, f);
    unsigned int r = (x + 0x7FFFu + ((x >> 16) & 1u)) >> 16;   // RNE
    return (unsigned short)r;
}

// ---------------------------------------------------------------------------
// k_prep: 256 blocks x 512 thr (VERBATIM from the R0 session kernel; passed).
//  (a) x fp32 -> bf16 xb + copy x into out[:, :8192]  (8 units x 512 float4)
//  (b) T (8192x1024 f32) -> Tt (1024x8192 bf16), 64x64 LDS tiles, 2 at a time
// Rationale (R12 post-mortem): gemm-from-fp32 requests 256 MB (x x8, T x4
// redundancy) at the ~6.15 TB/s memory-path ceiling = the invariant 41us.
// bf16 operands halve requested bytes AND shrink the per-XCD working set
// 6MB -> 3MB (< 4MB L2), turning redundant reads into L2 hits.
// ---------------------------------------------------------------------------
__global__ __launch_bounds__(512, 2) void k_prep(const float* __restrict__ x,
                                                 const float* __restrict__ T,
                                                 unsigned short* __restrict__ xb,
                                                 unsigned short* __restrict__ Tt,
                                                 float* __restrict__ out) {
    __shared__ __align__(16) float lds[2][64][65];   // +1 pad: 2-way only (free)
    int bid = blockIdx.x, t = threadIdx.x;
#pragma unroll
    for (int u = 0; u < 8; ++u) {
        int gid = bid * 4096 + u * 512 + t;          // float4 index, 1M total
        float4 v = *(const float4*)(x + (size_t)gid * 4);
        ushort4 uu;
        uu.x = f2bf(v.x); uu.y = f2bf(v.y); uu.z = f2bf(v.z); uu.w = f2bf(v.w);
        *(ushort4*)(xb + (size_t)gid * 4) = uu;
        int row = gid >> 11, col4 = gid & 2047;
        *(float4*)(out + (size_t)row * OUTC + col4 * 4) = v;
    }
    // T transpose: 2048 tiles of 64x64; 8 per block, 2 concurrently
    int sub = t >> 8, tt = t & 255;
    for (int u = 0; u < 4; ++u) {
        int tile = bid * 8 + u * 2 + sub;
        int kt = tile & 127, nt = tile >> 7;         // 128 k-tiles x 16 n-tiles
        __syncthreads();                              // protect prior reads
        int kk = tt >> 2, q = tt & 3;
#pragma unroll
        for (int p = 0; p < 4; ++p) {
            int c4 = q + p * 4;
            float4 v = *(const float4*)(T + (size_t)(kt * 64 + kk) * MCOLS + nt * 64 + c4 * 4);
            lds[sub][kk][c4 * 4 + 0] = v.x; lds[sub][kk][c4 * 4 + 1] = v.y;
            lds[sub][kk][c4 * 4 + 2] = v.z; lds[sub][kk][c4 * 4 + 3] = v.w;
        }
        __syncthreads();
        int nr = tt >> 2, ck = tt & 3;
        unsigned int wv[8];
#pragma unroll
        for (int j = 0; j < 8; ++j) {
            unsigned int lo = f2bf(lds[sub][ck * 16 + j * 2 + 0][nr]);
            unsigned int hi = f2bf(lds[sub][ck * 16 + j * 2 + 1][nr]);
            wv[j] = lo | (hi << 16);
        }
        uint4* dst = (uint4*)(Tt + (size_t)(nt * 64 + nr) * FEAT + kt * 64 + ck * 16);
        dst[0] = make_uint4(wv[0], wv[1], wv[2], wv[3]);
        dst[1] = make_uint4(wv[4], wv[5], wv[6], wv[7]);
    }
}

// ---------------------------------------------------------------------------
// k_gemm: M = xb@Tt^T (both bf16). 128x128 tile, 8 waves 2x4, BK=64,
// split-K=8, grid 256, launch_bounds(512,2). XCD swizzle puts one ks-chunk
// per XCD: working set xb-chunk 1MB + Tt-chunk 2MB = 3MB < 4MB L2 ->
// redundant cross-block reads are L2 hits (36.9 TB/s tier, m56).
// Staging: 4 x 16B loads/thread/step, direct ds_write_b128 into the same
// XOR-swizzled layout as R12 (slot = chunk ^ s(row), s(r)=(r&7)^((r>>2)&7)).
// R12 barrier schedule kept verbatim: dbuf LDS, raw s_barrier + lgkmcnt(0)
// only, dist-2 named register sets + KEEP pin, vmcnt never drained in-loop.
// Epilogue: Mp[ks][b_idx][row][c] (R12's pair-friendly layout, measured +3.5us).
// ---------------------------------------------------------------------------
__global__ __launch_bounds__(512, 2) void k_gemm(const unsigned short* __restrict__ xb,
                                                 const unsigned short* __restrict__ Tt,
                                                 float* __restrict__ Mp) {
    __shared__ __align__(16) unsigned short ldsA[2][128 * 64];   // 2 x 16 KB
    __shared__ __align__(16) unsigned short ldsB[2][128 * 64];   // 2 x 16 KB
    char* ldsAc = (char*)ldsA;
    char* ldsBc = (char*)ldsB;

    int bid = blockIdx.x;
    int wg = (bid & 7) * 32 + (bid >> 3);        // XCD-contiguous remap; ks==XCD
    int mt = wg & 3, nt = (wg >> 2) & 7, ks = wg >> 5;   // ks in 0..7
    int m0 = mt * 128, n0 = nt * 128, kbase = ks * KCHUNK;
    int t = threadIdx.x, w = t >> 6, l = t & 63;

    // ---- staging geometry: 128 rows x 64 k (128 B/row); 4 thr/row, 2 chunks
    int srow = t >> 2, c = t & 3;                // rows 0..127, chunks c, c+4
    const unsigned short* gA = xb + (size_t)(m0 + srow) * FEAT + kbase + c * 8;
    const unsigned short* gB = Tt + (size_t)(n0 + srow) * FEAT + kbase + c * 8;
    int sws = (srow & 7) ^ ((srow >> 2) & 7);
    int wS1 = srow * 128 + ((c ^ sws) << 4);     // byte offset in LDS panel
    int wS2 = wS1 ^ 64;                          // chunk c+4 -> slot bit2 flip

    // ---- compute geometry: wave (wr=w>>2, wc=w&3) owns 64x32 of C
    int wr = w >> 2, wc = w & 3, fm = l & 15, fq = l >> 4;
    int swf = (fm & 7) ^ ((fm >> 2) & 7);
    int baseA = (wr * 64 + fm) * 128 + ((fq ^ swf) << 4);
    int baseB = (wc * 32 + fm) * 128 + ((fq ^ swf) << 4);

    floatx4 acc[4][2] = {};

    // two named-scalar staging sets (KEEP pins them live as distinct regs)
    uint4 a01, a02, b01, b02;                    // set 0
    uint4 a11, a12, b11, b12;                    // set 1

#define ISSUE(A1, A2, B1, B2, KK) do {                                      \
        const unsigned short* pa_ = gA + (KK) * 64;                         \
        A1 = *(const uint4*)(pa_);                                          \
        A2 = *(const uint4*)(pa_ + 32);                                     \
        const unsigned short* pb_ = gB + (KK) * 64;                         \
        B1 = *(const uint4*)(pb_);                                          \
        B2 = *(const uint4*)(pb_ + 32);                                     \
    } while (0)

#define KEEP(A1, A2, B1, B2)                                                \
    asm volatile("" ::                                                      \
        "v"(A1.x), "v"(A1.y), "v"(A1.z), "v"(A1.w),                         \
        "v"(A2.x), "v"(A2.y), "v"(A2.z), "v"(A2.w),                         \
        "v"(B1.x), "v"(B1.y), "v"(B1.z), "v"(B1.w),                         \
        "v"(B2.x), "v"(B2.y), "v"(B2.z), "v"(B2.w))

#define WRITE(A1, A2, B1, B2, SO) do {                                      \
        *(uint4*)(ldsAc + (SO) + wS1) = A1;                                 \
        *(uint4*)(ldsAc + (SO) + wS2) = A2;                                 \
        *(uint4*)(ldsBc + (SO) + wS1) = B1;                                 \
        *(uint4*)(ldsBc + (SO) + wS2) = B2;                                 \
    } while (0)

#define MFMA_PHASE(SO) do {                                                 \
        _Pragma("unroll")                                                   \
        for (int h = 0; h < 2; ++h) {                                       \
            bf16x8 af[4], bfr[2];                                           \
            _Pragma("unroll")                                               \
            for (int a = 0; a < 4; ++a)                                     \
                af[a] = *(const bf16x8*)(ldsAc + (SO) + ((baseA + a * 2048) ^ ((h ^ (a & 1)) << 6))); \
            _Pragma("unroll")                                               \
            for (int b = 0; b < 2; ++b)                                     \
                bfr[b] = *(const bf16x8*)(ldsBc + (SO) + ((baseB + b * 2048) ^ ((h ^ (b & 1)) << 6))); \
            _Pragma("unroll")                                               \
            for (int a = 0; a < 4; ++a)                                     \
                _Pragma("unroll")                                           \
                for (int b = 0; b < 2; ++b)                                 \
                    acc[a][b] = __builtin_amdgcn_mfma_f32_16x16x32_bf16(af[a], bfr[b], acc[a][b], 0, 0, 0); \
        }                                                                   \
    } while (0)

    ISSUE(a01, a02, b01, b02, 0);
    ISSUE(a11, a12, b11, b12, 1);
    for (int kk = 0; kk < KSTEPS; kk += 2) {
        // ---- step kk (buffer 0, set 0)
        WRITE(a01, a02, b01, b02, 0);
        if (kk + 2 < KSTEPS) ISSUE(a01, a02, b01, b02, kk + 2);
        asm volatile("s_waitcnt lgkmcnt(0)" ::: "memory");
        __builtin_amdgcn_sched_barrier(0);
        __builtin_amdgcn_s_barrier();
        MFMA_PHASE(0);
        KEEP(a11, a12, b11, b12);                // set1 ready
        // ---- step kk+1 (buffer 1, set 1)
        WRITE(a11, a12, b11, b12, 16384);
        if (kk + 3 < KSTEPS) ISSUE(a11, a12, b11, b12, kk + 3);
        asm volatile("s_waitcnt lgkmcnt(0)" ::: "memory");
        __builtin_amdgcn_sched_barrier(0);
        __builtin_amdgcn_s_barrier();
        MFMA_PHASE(16384);
        KEEP(a01, a02, b01, b02);                // set0 ready
    }
#undef ISSUE
#undef KEEP
#undef WRITE
#undef MFMA_PHASE

    // epilogue: Mp layout [ks][b_idx][row][c]; b_idx = col>>4, c = fm.
    float* outp = Mp + (size_t)ks * MSIZE;
    int b0 = nt * 8 + wc * 2;                    // (n0 + wc*32) >> 4
    int gr0 = m0 + wr * 64;
#pragma unroll
    for (int a = 0; a < 4; ++a)
#pragma unroll
        for (int r = 0; r < 4; ++r) {
            int row = gr0 + a * 16 + fq * 4 + r;
#pragma unroll
            for (int b = 0; b < 2; ++b)
                outp[(size_t)(b0 + b) * (NROWS * CDIM) + row * CDIM + fm] = acc[a][b][r];
        }
}

// ---------------------------------------------------------------------------
// k_pair: o[i,b] = sum_j exp(-L1(M_i,M_j)) -> out[:, 8192:8256].
// Verbatim R12 (measured +3.5us win): Mp [ks][b][j][c] -> staging is 8
// fully-linear coalesced streams; ldsM [512][16]; jj wave-uniform broadcast.
// ---------------------------------------------------------------------------
__global__ __launch_bounds__(512, 1) void k_pair(const float* __restrict__ Mp,
                                                 float* __restrict__ out) {
    __shared__ __align__(16) float ldsM[NROWS * CDIM];   // 32 KB
    __shared__ float partial[8][64];
    int bid = blockIdx.x, t = threadIdx.x;
    int b = bid & 63, itp = bid >> 6;
    const float* slab = Mp + (size_t)b * (NROWS * CDIM);

#pragma unroll
    for (int p = 0; p < 4; ++p) {
        int idx = t + p * 512;                   // 2048 float4, linear
        float4 s = *(const float4*)(slab + (size_t)idx * 4);
#pragma unroll
        for (int k = 1; k < KSPLIT; ++k) {
            float4 v = *(const float4*)(slab + (size_t)k * MSIZE + (size_t)idx * 4);
            s.x += v.x; s.y += v.y; s.z += v.z; s.w += v.w;
        }
        *(float4*)&ldsM[idx * 4] = s;
    }
    __syncthreads();

    int lane = t & 63, w = t >> 6, g = t >> 8, wg = (t >> 6) & 3;
    int i = (itp * 2 + g) * 64 + lane;
    float4 mi0 = *(const float4*)&ldsM[i * CDIM + 0];
    float4 mi1 = *(const float4*)&ldsM[i * CDIM + 4];
    float4 mi2 = *(const float4*)&ldsM[i * CDIM + 8];
    float4 mi3 = *(const float4*)&ldsM[i * CDIM + 12];

    float acc = 0.0f;
    for (int jj = wg * 128; jj < wg * 128 + 128; ++jj) {
        const float4* rp = (const float4*)&ldsM[jj * CDIM];
        float4 a0 = rp[0], a1 = rp[1], a2 = rp[2], a3 = rp[3];
        float d = fabsf(mi0.x - a0.x) + fabsf(mi0.y - a0.y)
                + fabsf(mi0.z - a0.z) + fabsf(mi0.w - a0.w)
                + fabsf(mi1.x - a1.x) + fabsf(mi1.y - a1.y)
                + fabsf(mi1.z - a1.z) + fabsf(mi1.w - a1.w)
                + fabsf(mi2.x - a2.x) + fabsf(mi2.y - a2.y)
                + fabsf(mi2.z - a2.z) + fabsf(mi2.w - a2.w)
                + fabsf(mi3.x - a3.x) + fabsf(mi3.y - a3.y)
                + fabsf(mi3.z - a3.z) + fabsf(mi3.w - a3.w);
        acc += __expf(-d);
    }
    partial[w][lane] = acc;
    __syncthreads();
    if ((t & 255) < 64) {
        int ii = (itp * 2 + g) * 64 + (t & 63);
        float o = partial[g * 4 + 0][t & 63] + partial[g * 4 + 1][t & 63] +
                  partial[g * 4 + 2][t & 63] + partial[g * 4 + 3][t & 63];
        out[(size_t)ii * OUTC + FEAT + b] = o;
    }
}

// ---------------------------------------------------------------------------
extern "C" void kernel_launch(void* const* d_in, const int* in_sizes, int n_in,
                              void* d_out, int out_size, void* d_ws, size_t ws_size,
                              hipStream_t stream) {
    const float* x = (const float*)d_in[0];      // (512, 8192)
    const float* T = (const float*)d_in[1];      // (8192, 1024)
    float* out = (float*)d_out;                  // (512, 8256)

    // ws layout: xb 8MB | Tt 16MB | Mp 8x2MB=16MB  (40MB total)
    unsigned short* xb = (unsigned short*)d_ws;
    unsigned short* Tt = (unsigned short*)((char*)d_ws + (8u << 20));
    float*          Mp = (float*)((char*)d_ws + (24u << 20));

    k_prep<<<256, 512, 0, stream>>>(x, T, xb, Tt, out);
    k_gemm<<<256, 512, 0, stream>>>(xb, Tt, Mp);
    k_pair<<<256, 512, 0, stream>>>(Mp, out);
}